// Round 1
// baseline (47.538 us; speedup 1.0000x reference)
//
#include <hip/hip_runtime.h>

#define SCAN_BS 1024
#define OBJ_BS  256

// ---------------- prefix scan of per-CAV counts ----------------

__global__ void scan_blocks_kernel(const int* __restrict__ counts, int C,
                                   int* __restrict__ offsets, int* __restrict__ blockSums) {
    __shared__ int sdata[SCAN_BS];
    int tid = threadIdx.x;
    int gid = blockIdx.x * SCAN_BS + tid;
    int v = (gid < C) ? counts[gid] : 0;
    sdata[tid] = v;
    __syncthreads();
    // Hillis-Steele inclusive scan
    for (int ofs = 1; ofs < SCAN_BS; ofs <<= 1) {
        int add = (tid >= ofs) ? sdata[tid - ofs] : 0;
        __syncthreads();
        sdata[tid] += add;
        __syncthreads();
    }
    if (gid < C) offsets[gid] = sdata[tid];
    if (tid == SCAN_BS - 1) blockSums[blockIdx.x] = sdata[tid];
}

// single block: scan block sums, store EXCLUSIVE prefix back
__global__ void scan_sums_kernel(int* __restrict__ blockSums, int nb) {
    __shared__ int sdata[SCAN_BS];
    int tid = threadIdx.x;
    int v = (tid < nb) ? blockSums[tid] : 0;
    sdata[tid] = v;
    __syncthreads();
    for (int ofs = 1; ofs < SCAN_BS; ofs <<= 1) {
        int add = (tid >= ofs) ? sdata[tid - ofs] : 0;
        __syncthreads();
        sdata[tid] += add;
        __syncthreads();
    }
    if (tid < nb) blockSums[tid] = sdata[tid] - v;  // exclusive
}

__global__ void add_offsets_kernel(int* __restrict__ offsets, const int* __restrict__ blockSums, int C) {
    int gid = blockIdx.x * SCAN_BS + threadIdx.x;
    if (gid < C) offsets[gid] += blockSums[blockIdx.x];
}

// ---------------- main per-object kernel ----------------
//
// out layout (floats):
//   [0,       8N)  obj_input  [1,N,2,4]
//   [8N,     10N)  query      [1,N,1,2]
//   [10N,    12N)  time_encode[N,2]
//   [12N,    13N)  target_time_diff [N]

__global__ __launch_bounds__(OBJ_BS) void motion_kernel(
    const float* __restrict__ bbx, const float* __restrict__ tint,
    const int* __restrict__ offsets, int C, int N,
    float* __restrict__ out) {

    __shared__ __align__(16) float sb[OBJ_BS * 21];

    const int tid = threadIdx.x;
    const long long blockStart = (long long)blockIdx.x * OBJ_BS;
    const int nObjBlk = (int)min((long long)OBJ_BS, (long long)N - blockStart);
    const int nElem = nObjBlk * 21;

    // stage bbx slab: coalesced float4 loads (gsrc is 16B aligned: blockStart*84 % 16 == 0)
    const float* gsrc = bbx + blockStart * 21;
    const int nv = nElem >> 2;
    {
        float4* sv = (float4*)sb;
        const float4* gv = (const float4*)gsrc;
        for (int k = tid; k < nv; k += OBJ_BS) sv[k] = gv[k];
        for (int k = (nv << 2) + tid; k < nElem; k += OBJ_BS) sb[k] = gsrc[k];
    }
    __syncthreads();

    if (tid >= nObjBlk) return;
    const int i = (int)(blockStart + tid);

    // cav index: first c with offsets[c] > i  (searchsorted side='right' on cumsum)
    int lo = 0, hi = C;
    while (lo < hi) {
        int mid = (lo + hi) >> 1;
        if (offsets[mid] > i) hi = mid; else lo = mid + 1;
    }
    const int c = lo;
    const float t0 = tint[c * 3 + 0];
    const float t1 = tint[c * 3 + 1];
    const float t2 = tint[c * 3 + 2];

    // td_rep = [t2, t1, t0];  dt = time_encode
    const float dt0 = t1 - t2;
    const float dt1 = t0 - t1;

    // frames from LDS: frame k at sb[tid*21 + k*7 + {0,1}]
    const float* b = sb + tid * 21;
    const float x0 = b[0],  y0 = b[1];
    const float x1 = b[7],  y1 = b[8];
    const float x2 = b[14], y2 = b[15];

    // coords (flipped, normalized to last): c0 = bbx2-bbx0, c1 = bbx1-bbx0, c2 = 0
    const float c0x = x2 - x0, c0y = y2 - y0;
    const float c1x = x1 - x0, c1y = y1 - y0;

    // distance (faithful FP order: coords[j+1]-coords[j])
    const float d0x = c1x - c0x, d0y = c1y - c0y;
    const float d1x = 0.0f - c1x, d1y = 0.0f - c1y;

    const float s0x = d0x / dt0, s0y = d0y / dt0;
    const float s1x = d1x / dt1, s1y = d1y / dt1;

    // last_len = td_norm[-1]-td_norm[-2] = 0 - (t1 - t0)  (== dt1 bit-exact)
    const float last_len = 0.0f - (t1 - t0);
    const float safe_len = (last_len == 0.0f) ? 1.0f : last_len;
    // extrap = c2 + (c2 - c1)*(-t0)/safe_len, with c2 == 0
    const float exx = ((0.0f - c1x) * (0.0f - t0)) / safe_len;
    const float exy = ((0.0f - c1y) * (0.0f - t0)) / safe_len;
    const float qx = (last_len == 0.0f) ? 0.0f : exx;
    const float qy = (last_len == 0.0f) ? 0.0f : exy;

    // ---- writes ----
    const size_t Ns = (size_t)N;
    float4* oi = (float4*)out;                 // obj_input as float4 pairs
    oi[(size_t)i * 2 + 0] = make_float4(d0x, d0y, s0x, s0y);
    oi[(size_t)i * 2 + 1] = make_float4(d1x, d1y, s1x, s1y);

    float2* q  = (float2*)(out + 8 * Ns);
    q[i] = make_float2(qx, qy);

    float2* te = (float2*)(out + 10 * Ns);
    te[i] = make_float2(dt0, dt1);

    out[12 * Ns + (size_t)i] = 0.0f - t0;      // target_time_diff = -td_rep[:,-1]
}

// ---------------- launch ----------------

extern "C" void kernel_launch(void* const* d_in, const int* in_sizes, int n_in,
                              void* d_out, int out_size, void* d_ws, size_t ws_size,
                              hipStream_t stream) {
    const float* bbx  = (const float*)d_in[0];   // [N,3,7]
    const float* tint = (const float*)d_in[1];   // [C*3]
    const int*   cnt  = (const int*)d_in[2];     // [C]
    float* out = (float*)d_out;

    const int N = in_sizes[0] / 21;
    const int C = in_sizes[2];

    int* offsets   = (int*)d_ws;        // C ints
    const int nb   = (C + SCAN_BS - 1) / SCAN_BS;
    int* blockSums = offsets + C;       // nb ints

    scan_blocks_kernel<<<nb, SCAN_BS, 0, stream>>>(cnt, C, offsets, blockSums);
    scan_sums_kernel<<<1, SCAN_BS, 0, stream>>>(blockSums, nb);
    add_offsets_kernel<<<nb, SCAN_BS, 0, stream>>>(offsets, blockSums, C);

    const int ob = (N + OBJ_BS - 1) / OBJ_BS;
    motion_kernel<<<ob, OBJ_BS, 0, stream>>>(bbx, tint, offsets, C, N, out);
}

// Round 2
// 43.198 us; speedup vs baseline: 1.1005x; 1.1005x over previous
//
#include <hip/hip_runtime.h>
#include <limits.h>

#define SCAN_BS 1024
#define OBJ_BS  256

// ---------------- prefix scan of per-CAV counts ----------------

__global__ void scan_blocks_kernel(const int* __restrict__ counts, int C,
                                   int* __restrict__ offsets, int* __restrict__ blockSums) {
    __shared__ int sdata[SCAN_BS];
    int tid = threadIdx.x;
    int gid = blockIdx.x * SCAN_BS + tid;
    int v = (gid < C) ? counts[gid] : 0;
    sdata[tid] = v;
    __syncthreads();
    for (int ofs = 1; ofs < SCAN_BS; ofs <<= 1) {
        int add = (tid >= ofs) ? sdata[tid - ofs] : 0;
        __syncthreads();
        sdata[tid] += add;
        __syncthreads();
    }
    if (gid < C) offsets[gid] = sdata[tid];
    if (tid == SCAN_BS - 1) blockSums[blockIdx.x] = sdata[tid];
}

// single block: scan block sums, store EXCLUSIVE prefix back
__global__ void scan_sums_kernel(int* __restrict__ blockSums, int nb) {
    __shared__ int sdata[SCAN_BS];
    int tid = threadIdx.x;
    int v = (tid < nb) ? blockSums[tid] : 0;
    sdata[tid] = v;
    __syncthreads();
    for (int ofs = 1; ofs < SCAN_BS; ofs <<= 1) {
        int add = (tid >= ofs) ? sdata[tid - ofs] : 0;
        __syncthreads();
        sdata[tid] += add;
        __syncthreads();
    }
    if (tid < nb) blockSums[tid] = sdata[tid] - v;  // exclusive
}

// finalize offsets AND fill blockCav: blockCav[b] = cav containing object b*OBJ_BS
__global__ void add_offsets_blockcav_kernel(int* __restrict__ offsets,
                                            const int* __restrict__ blockSums,
                                            const int* __restrict__ counts, int C,
                                            int* __restrict__ blockCav) {
    int gid = blockIdx.x * SCAN_BS + threadIdx.x;
    if (gid >= C) return;
    int end = offsets[gid] + blockSums[blockIdx.x];
    offsets[gid] = end;
    int start = end - counts[gid];
    // block starts (multiples of OBJ_BS) inside [start, end)
    int s0 = ((start + OBJ_BS - 1) / OBJ_BS) * OBJ_BS;
    for (int s = s0; s < end; s += OBJ_BS) blockCav[s / OBJ_BS] = gid;
}

// ---------------- main per-object kernel ----------------
//
// out layout (floats):
//   [0,       8N)  obj_input  [1,N,2,4]
//   [8N,     10N)  query      [1,N,1,2]
//   [10N,    12N)  time_encode[N,2]
//   [12N,    13N)  target_time_diff [N]

__global__ __launch_bounds__(OBJ_BS) void motion_kernel(
    const float* __restrict__ bbx, const float* __restrict__ tint,
    const int* __restrict__ offsets, const int* __restrict__ blockCav,
    int C, int N, float* __restrict__ out) {

    __shared__ __align__(16) float sb[OBJ_BS * 21];
    __shared__ int   soff[OBJ_BS + 1];        // offsets[c_lo .. c_lo+256]
    __shared__ float st[3 * (OBJ_BS + 1)];    // tint rows for those cavs

    const int tid = threadIdx.x;
    const long long blockStart = (long long)blockIdx.x * OBJ_BS;
    const int nObjBlk = (int)min((long long)OBJ_BS, (long long)N - blockStart);
    const int nElem = nObjBlk * 21;

    const int c_lo = blockCav[blockIdx.x];    // uniform -> scalar load

    // stage offsets slab (257 ints, coalesced; INT_MAX sentinel past end)
    {
        int c = c_lo + tid;
        soff[tid] = (c < C) ? offsets[c] : INT_MAX;
        if (tid == 0) {
            int c2 = c_lo + OBJ_BS;
            soff[OBJ_BS] = (c2 < C) ? offsets[c2] : INT_MAX;
        }
    }
    // stage tint slab (771 floats, coalesced)
    {
        const int base = 3 * c_lo;
        const int lim  = 3 * C - base;
        for (int k = tid; k < 3 * (OBJ_BS + 1); k += OBJ_BS)
            st[k] = (k < lim) ? tint[base + k] : 0.0f;
    }
    // stage bbx slab: coalesced float4 loads (blockStart*84 % 16 == 0)
    const float* gsrc = bbx + blockStart * 21;
    const int nv = nElem >> 2;
    {
        float4* sv = (float4*)sb;
        const float4* gv = (const float4*)gsrc;
        for (int k = tid; k < nv; k += OBJ_BS) sv[k] = gv[k];
        for (int k = (nv << 2) + tid; k < nElem; k += OBJ_BS) sb[k] = gsrc[k];
    }
    __syncthreads();

    if (tid >= nObjBlk) return;
    const int i = (int)(blockStart + tid);

    // binary search in LDS: first j in [0,257) with soff[j] > i
    int lo = 0, hi = OBJ_BS + 1;
    while (lo < hi) {
        int mid = (lo + hi) >> 1;
        if (soff[mid] > i) hi = mid; else lo = mid + 1;
    }
    const int j = lo;
    const float t0 = st[3 * j + 0];
    const float t1 = st[3 * j + 1];
    const float t2 = st[3 * j + 2];

    // td_rep = [t2, t1, t0];  dt = time_encode
    const float dt0 = t1 - t2;
    const float dt1 = t0 - t1;

    // frames from LDS: frame k at sb[tid*21 + k*7 + {0,1}]
    const float* b = sb + tid * 21;
    const float x0 = b[0],  y0 = b[1];
    const float x1 = b[7],  y1 = b[8];
    const float x2 = b[14], y2 = b[15];

    // coords (flipped, normalized to last): c0 = bbx2-bbx0, c1 = bbx1-bbx0, c2 = 0
    const float c0x = x2 - x0, c0y = y2 - y0;
    const float c1x = x1 - x0, c1y = y1 - y0;

    // distance (faithful FP order: coords[j+1]-coords[j])
    const float d0x = c1x - c0x, d0y = c1y - c0y;
    const float d1x = 0.0f - c1x, d1y = 0.0f - c1y;

    const float s0x = d0x / dt0, s0y = d0y / dt0;
    const float s1x = d1x / dt1, s1y = d1y / dt1;

    // last_len = 0 - (t1 - t0)
    const float last_len = 0.0f - (t1 - t0);
    const float safe_len = (last_len == 0.0f) ? 1.0f : last_len;
    const float exx = ((0.0f - c1x) * (0.0f - t0)) / safe_len;
    const float exy = ((0.0f - c1y) * (0.0f - t0)) / safe_len;
    const float qx = (last_len == 0.0f) ? 0.0f : exx;
    const float qy = (last_len == 0.0f) ? 0.0f : exy;

    // ---- writes ----
    const size_t Ns = (size_t)N;
    float4* oi = (float4*)out;
    oi[(size_t)i * 2 + 0] = make_float4(d0x, d0y, s0x, s0y);
    oi[(size_t)i * 2 + 1] = make_float4(d1x, d1y, s1x, s1y);

    float2* q  = (float2*)(out + 8 * Ns);
    q[i] = make_float2(qx, qy);

    float2* te = (float2*)(out + 10 * Ns);
    te[i] = make_float2(dt0, dt1);

    out[12 * Ns + (size_t)i] = 0.0f - t0;
}

// ---------------- launch ----------------

extern "C" void kernel_launch(void* const* d_in, const int* in_sizes, int n_in,
                              void* d_out, int out_size, void* d_ws, size_t ws_size,
                              hipStream_t stream) {
    const float* bbx  = (const float*)d_in[0];   // [N,3,7]
    const float* tint = (const float*)d_in[1];   // [C*3]
    const int*   cnt  = (const int*)d_in[2];     // [C]
    float* out = (float*)d_out;

    const int N = in_sizes[0] / 21;
    const int C = in_sizes[2];

    int* offsets   = (int*)d_ws;                   // C ints
    const int nb   = (C + SCAN_BS - 1) / SCAN_BS;
    int* blockSums = offsets + C;                  // nb ints
    const int ob   = (N + OBJ_BS - 1) / OBJ_BS;
    int* blockCav  = blockSums + nb;               // ob ints

    scan_blocks_kernel<<<nb, SCAN_BS, 0, stream>>>(cnt, C, offsets, blockSums);
    scan_sums_kernel<<<1, SCAN_BS, 0, stream>>>(blockSums, nb);
    add_offsets_blockcav_kernel<<<nb, SCAN_BS, 0, stream>>>(offsets, blockSums, cnt, C, blockCav);

    motion_kernel<<<ob, OBJ_BS, 0, stream>>>(bbx, tint, offsets, blockCav, C, N, out);
}

// Round 3
// 36.389 us; speedup vs baseline: 1.3064x; 1.1871x over previous
//
#include <hip/hip_runtime.h>
#include <limits.h>
#include <stdint.h>

#define SCAN_BS 1024
#define OBJ_BS  256
#define SLAB_F  (OBJ_BS * 21)        // 5376 floats = 21504 B per slab
#define SLAB_V4 (SLAB_F / 4)         // 1344 float4
#define SLAB_CH (SLAB_V4 / 64)       // 21 wave-chunks of 64 float4

// ---------------- prefix scan of per-CAV counts ----------------

__global__ void scan_blocks_kernel(const int* __restrict__ counts, int C,
                                   int* __restrict__ offsets, int* __restrict__ blockSums) {
    __shared__ int sdata[SCAN_BS];
    int tid = threadIdx.x;
    int gid = blockIdx.x * SCAN_BS + tid;
    int v = (gid < C) ? counts[gid] : 0;
    sdata[tid] = v;
    __syncthreads();
    for (int ofs = 1; ofs < SCAN_BS; ofs <<= 1) {
        int add = (tid >= ofs) ? sdata[tid - ofs] : 0;
        __syncthreads();
        sdata[tid] += add;
        __syncthreads();
    }
    if (gid < C) offsets[gid] = sdata[tid];
    if (tid == SCAN_BS - 1) blockSums[blockIdx.x] = sdata[tid];
}

__global__ void scan_sums_kernel(int* __restrict__ blockSums, int nb) {
    __shared__ int sdata[SCAN_BS];
    int tid = threadIdx.x;
    int v = (tid < nb) ? blockSums[tid] : 0;
    sdata[tid] = v;
    __syncthreads();
    for (int ofs = 1; ofs < SCAN_BS; ofs <<= 1) {
        int add = (tid >= ofs) ? sdata[tid - ofs] : 0;
        __syncthreads();
        sdata[tid] += add;
        __syncthreads();
    }
    if (tid < nb) blockSums[tid] = sdata[tid] - v;  // exclusive
}

// finalize offsets AND fill blockCav: blockCav[b] = cav containing object b*OBJ_BS
__global__ void add_offsets_blockcav_kernel(int* __restrict__ offsets,
                                            const int* __restrict__ blockSums,
                                            const int* __restrict__ counts, int C,
                                            int* __restrict__ blockCav) {
    int gid = blockIdx.x * SCAN_BS + threadIdx.x;
    if (gid >= C) return;
    int end = offsets[gid] + blockSums[blockIdx.x];
    offsets[gid] = end;
    int start = end - counts[gid];
    int s0 = ((start + OBJ_BS - 1) / OBJ_BS) * OBJ_BS;
    for (int s = s0; s < end; s += OBJ_BS) blockCav[s / OBJ_BS] = gid;
}

// ---------------- main per-object kernel ----------------
//
// out layout (floats):
//   [0,       8N)  obj_input  [1,N,2,4]
//   [8N,     10N)  query      [1,N,1,2]
//   [10N,    12N)  time_encode[N,2]
//   [12N,    13N)  target_time_diff [N]

__device__ __forceinline__ void gload_lds16(const void* g, void* l) {
    __builtin_amdgcn_global_load_lds(
        (const __attribute__((address_space(1))) uint32_t*)g,
        (__attribute__((address_space(3))) uint32_t*)l, 16, 0, 0);
}

__global__ __launch_bounds__(OBJ_BS) void motion_kernel(
    const float* __restrict__ bbx, const float* __restrict__ tint,
    const int* __restrict__ offsets, const int* __restrict__ blockCav,
    int C, int N, float* __restrict__ out) {

    __shared__ __align__(16) float sb[SLAB_F];
    __shared__ int   soff[OBJ_BS + 1];        // offsets[c_lo .. c_lo+256]
    __shared__ float st[3 * (OBJ_BS + 1)];    // tint rows for those cavs (771)

    const int tid  = threadIdx.x;
    const int lane = tid & 63;
    const int wid  = tid >> 6;
    const long long blockStart = (long long)blockIdx.x * OBJ_BS;
    const int nObjBlk = (int)min((long long)OBJ_BS, (long long)N - blockStart);

    const int c_lo = blockCav[blockIdx.x];    // uniform -> scalar load

    // ---- issue bbx slab DMA (fire-and-forget, no VGPR round trip) ----
    const float* gsrc = bbx + blockStart * 21;
    if (nObjBlk == OBJ_BS) {
        const float4* gv = (const float4*)gsrc;
        #pragma unroll
        for (int ch = wid; ch < SLAB_CH; ch += 4)
            gload_lds16((const void*)(gv + ch * 64 + lane), (void*)(sb + ch * 64 * 4));
    } else {
        // tail fallback (not hit when N % 256 == 0)
        const int nElem = nObjBlk * 21;
        for (int k = tid; k < nElem; k += OBJ_BS) sb[k] = gsrc[k];
    }

    // ---- side loads: all issued independently, then LDS writes ----
    const int c = c_lo + tid;
    const int offv = (c < C) ? offsets[c] : INT_MAX;
    int off_last = INT_MAX;
    if (tid == 0) {
        int c2 = c_lo + OBJ_BS;
        off_last = (c2 < C) ? offsets[c2] : INT_MAX;
    }
    const int base3 = 3 * c_lo;
    const int lim3  = 3 * C - base3;
    const float tv0 = (tid < lim3)       ? tint[base3 + tid]       : 0.0f;
    const float tv1 = (tid + 256 < lim3) ? tint[base3 + tid + 256] : 0.0f;
    const float tv2 = (tid + 512 < lim3) ? tint[base3 + tid + 512] : 0.0f;
    float tv3 = 0.0f;
    if (tid < 3 && tid + 768 < lim3) tv3 = tint[base3 + tid + 768];

    soff[tid] = offv;
    if (tid == 0) soff[OBJ_BS] = off_last;
    st[tid]       = tv0;
    st[tid + 256] = tv1;
    st[tid + 512] = tv2;
    if (tid < 3) st[tid + 768] = tv3;

    __syncthreads();   // drains DMA (vmcnt) + LDS writes

    if (tid >= nObjBlk) return;
    const int i = (int)(blockStart + tid);

    // binary search in LDS: first j in [0,257) with soff[j] > i
    int lo = 0, hi = OBJ_BS + 1;
    while (lo < hi) {
        int mid = (lo + hi) >> 1;
        if (soff[mid] > i) hi = mid; else lo = mid + 1;
    }
    const int j = lo;
    const float t0 = st[3 * j + 0];
    const float t1 = st[3 * j + 1];
    const float t2 = st[3 * j + 2];

    // td_rep = [t2, t1, t0];  dt = time_encode
    const float dt0 = t1 - t2;
    const float dt1 = t0 - t1;

    // frames from LDS: frame k at sb[tid*21 + k*7 + {0,1}]  (stride 21 -> conflict-free)
    const float* b = sb + tid * 21;
    const float x0 = b[0],  y0 = b[1];
    const float x1 = b[7],  y1 = b[8];
    const float x2 = b[14], y2 = b[15];

    // coords (flipped, normalized to last): c0 = bbx2-bbx0, c1 = bbx1-bbx0, c2 = 0
    const float c0x = x2 - x0, c0y = y2 - y0;
    const float c1x = x1 - x0, c1y = y1 - y0;

    const float d0x = c1x - c0x, d0y = c1y - c0y;
    const float d1x = 0.0f - c1x, d1y = 0.0f - c1y;

    const float s0x = d0x / dt0, s0y = d0y / dt0;
    const float s1x = d1x / dt1, s1y = d1y / dt1;

    const float last_len = 0.0f - (t1 - t0);
    const float safe_len = (last_len == 0.0f) ? 1.0f : last_len;
    const float exx = ((0.0f - c1x) * (0.0f - t0)) / safe_len;
    const float exy = ((0.0f - c1y) * (0.0f - t0)) / safe_len;
    const float qx = (last_len == 0.0f) ? 0.0f : exx;
    const float qy = (last_len == 0.0f) ? 0.0f : exy;

    // ---- writes ----
    const size_t Ns = (size_t)N;
    float4* oi = (float4*)out;
    oi[(size_t)i * 2 + 0] = make_float4(d0x, d0y, s0x, s0y);
    oi[(size_t)i * 2 + 1] = make_float4(d1x, d1y, s1x, s1y);

    float2* q  = (float2*)(out + 8 * Ns);
    q[i] = make_float2(qx, qy);

    float2* te = (float2*)(out + 10 * Ns);
    te[i] = make_float2(dt0, dt1);

    out[12 * Ns + (size_t)i] = 0.0f - t0;
}

// ---------------- launch ----------------

extern "C" void kernel_launch(void* const* d_in, const int* in_sizes, int n_in,
                              void* d_out, int out_size, void* d_ws, size_t ws_size,
                              hipStream_t stream) {
    const float* bbx  = (const float*)d_in[0];   // [N,3,7]
    const float* tint = (const float*)d_in[1];   // [C*3]
    const int*   cnt  = (const int*)d_in[2];     // [C]
    float* out = (float*)d_out;

    const int N = in_sizes[0] / 21;
    const int C = in_sizes[2];

    int* offsets   = (int*)d_ws;                   // C ints
    const int nb   = (C + SCAN_BS - 1) / SCAN_BS;
    int* blockSums = offsets + C;                  // nb ints
    const int ob   = (N + OBJ_BS - 1) / OBJ_BS;
    int* blockCav  = blockSums + nb;               // ob ints

    scan_blocks_kernel<<<nb, SCAN_BS, 0, stream>>>(cnt, C, offsets, blockSums);
    scan_sums_kernel<<<1, SCAN_BS, 0, stream>>>(blockSums, nb);
    add_offsets_blockcav_kernel<<<nb, SCAN_BS, 0, stream>>>(offsets, blockSums, cnt, C, blockCav);

    motion_kernel<<<ob, OBJ_BS, 0, stream>>>(bbx, tint, offsets, blockCav, C, N, out);
}